// Round 4
// baseline (357.717 us; speedup 1.0000x reference)
//
#include <hip/hip_runtime.h>
#include <cstdint>
#include <cstddef>

typedef unsigned long long u64;
typedef unsigned int u32;

// Problem constants (from reference)
constexpr int N    = 50000;   // library size
constexpr int D    = 768;     // vision dim
constexpr int OD   = 384;     // option / answer dim
constexpr int TOPK = 25;

constexpr int BLOCKS  = 2048;
constexpr int THREADS = 256;                          // 4 waves
constexpr int WAVES_TOTAL = BLOCKS * (THREADS / 64);  // 8192

// chunk top-k: done by the LAST 64 ticketed blocks, one wave each
constexpr int TK_BLOCKS = 64;
constexpr int TK_CHUNK  = 782;               // 64*782 = 50048 >= 50000
constexpr int KPT       = 13;                // 64*13 = 832 >= 782
constexpr int NCAND     = TK_BLOCKS * TOPK;  // 1600

// ---------------------------------------------------------------------------
// Single fused kernel. Phase 1 (all 2048 blocks): cosine scores + exp partial
// sums. Boundary 1: release-ticket on counters[0]; the last 64 blocks become
// "finishers" (everyone else's phase-1 writes are complete & released once
// c1 reaches 2048). Phase 2 (finishers, wave 0): exact chunk top-25 in
// registers. Boundary 2: ticket on counters[1]; the last finisher runs
// phase 3: Z-reduction, 64-way sorted merge, oia gather, 3 dots, output.
// Spin safety: spinners are among the last 64 of 2048 blocks => >=1984 blocks
// already retired, far more free slots than the <=63 still-queued blocks need.
// ---------------------------------------------------------------------------
__global__ __launch_bounds__(THREADS)
void k_fused(const float* __restrict__ v,
             const float* __restrict__ n_feats,
             const float* __restrict__ n_answ,
             const float* __restrict__ o,
             const float* __restrict__ temp_vid,
             u32*   __restrict__ counters,   // [0]=c1 [1]=c2, memset 0 pre-kernel
             float* __restrict__ s_out,
             float* __restrict__ part,
             u64*   __restrict__ cand,
             float* __restrict__ out)
{
    const int tid  = threadIdx.x;
    const int lane = tid & 63;
    const int wib  = tid >> 6;

    __shared__ float wsum[4];
    __shared__ u32   tksh;
    // phase-3 storage (~15.6 KB total LDS)
    __shared__ u64   ck[NCAND];
    __shared__ float red[256];
    __shared__ float oiash[OD];
    __shared__ float topw[TOPK];
    __shared__ int   topi[TOPK];
    __shared__ float zsh;

    // ---------------- phase 1: scores + exp partials ----------------
    {
        const int gwave = blockIdx.x * 4 + wib;
        const float4* v4 = reinterpret_cast<const float4*>(v);
        const float4 va = v4[lane];
        const float4 vb = v4[lane + 64];
        const float4 vc = v4[lane + 128];

        float vsq = 0.f;
        vsq = fmaf(va.x, va.x, vsq); vsq = fmaf(va.y, va.y, vsq);
        vsq = fmaf(va.z, va.z, vsq); vsq = fmaf(va.w, va.w, vsq);
        vsq = fmaf(vb.x, vb.x, vsq); vsq = fmaf(vb.y, vb.y, vsq);
        vsq = fmaf(vb.z, vb.z, vsq); vsq = fmaf(vb.w, vb.w, vsq);
        vsq = fmaf(vc.x, vc.x, vsq); vsq = fmaf(vc.y, vc.y, vsq);
        vsq = fmaf(vc.z, vc.z, vsq); vsq = fmaf(vc.w, vc.w, vsq);
        #pragma unroll
        for (int off = 32; off; off >>= 1) vsq += __shfl_xor(vsq, off);
        const float inv_vn = 1.0f / fmaxf(sqrtf(vsq), 1e-12f);

        float esum = 0.f;
        for (int r = 2 * gwave; r < N; r += 2 * WAVES_TOTAL) {
            // N is even: r+1 < N always
            const float4* f0 = reinterpret_cast<const float4*>(n_feats + (size_t)r * D);
            const float4* f1 = reinterpret_cast<const float4*>(n_feats + (size_t)(r + 1) * D);
            const float4 a0 = f0[lane];
            const float4 a1 = f0[lane + 64];
            const float4 a2 = f0[lane + 128];
            const float4 b0 = f1[lane];
            const float4 b1 = f1[lane + 64];
            const float4 b2 = f1[lane + 128];

            float dA = 0.f, nA = 0.f, dB = 0.f, nB = 0.f;
            dA = fmaf(a0.x, va.x, dA); nA = fmaf(a0.x, a0.x, nA);
            dB = fmaf(b0.x, va.x, dB); nB = fmaf(b0.x, b0.x, nB);
            dA = fmaf(a0.y, va.y, dA); nA = fmaf(a0.y, a0.y, nA);
            dB = fmaf(b0.y, va.y, dB); nB = fmaf(b0.y, b0.y, nB);
            dA = fmaf(a0.z, va.z, dA); nA = fmaf(a0.z, a0.z, nA);
            dB = fmaf(b0.z, va.z, dB); nB = fmaf(b0.z, b0.z, nB);
            dA = fmaf(a0.w, va.w, dA); nA = fmaf(a0.w, a0.w, nA);
            dB = fmaf(b0.w, va.w, dB); nB = fmaf(b0.w, b0.w, nB);
            dA = fmaf(a1.x, vb.x, dA); nA = fmaf(a1.x, a1.x, nA);
            dB = fmaf(b1.x, vb.x, dB); nB = fmaf(b1.x, b1.x, nB);
            dA = fmaf(a1.y, vb.y, dA); nA = fmaf(a1.y, a1.y, nA);
            dB = fmaf(b1.y, vb.y, dB); nB = fmaf(b1.y, b1.y, nB);
            dA = fmaf(a1.z, vb.z, dA); nA = fmaf(a1.z, a1.z, nA);
            dB = fmaf(b1.z, vb.z, dB); nB = fmaf(b1.z, b1.z, nB);
            dA = fmaf(a1.w, vb.w, dA); nA = fmaf(a1.w, a1.w, nA);
            dB = fmaf(b1.w, vb.w, dB); nB = fmaf(b1.w, b1.w, nB);
            dA = fmaf(a2.x, vc.x, dA); nA = fmaf(a2.x, a2.x, nA);
            dB = fmaf(b2.x, vc.x, dB); nB = fmaf(b2.x, b2.x, nB);
            dA = fmaf(a2.y, vc.y, dA); nA = fmaf(a2.y, a2.y, nA);
            dB = fmaf(b2.y, vc.y, dB); nB = fmaf(b2.y, b2.y, nB);
            dA = fmaf(a2.z, vc.z, dA); nA = fmaf(a2.z, a2.z, nA);
            dB = fmaf(b2.z, vc.z, dB); nB = fmaf(b2.z, b2.z, nB);
            dA = fmaf(a2.w, vc.w, dA); nA = fmaf(a2.w, a2.w, nA);
            dB = fmaf(b2.w, vc.w, dB); nB = fmaf(b2.w, b2.w, nB);

            #pragma unroll
            for (int off = 32; off; off >>= 1) {
                dA += __shfl_xor(dA, off);
                nA += __shfl_xor(nA, off);
                dB += __shfl_xor(dB, off);
                nB += __shfl_xor(nB, off);
            }

            float sA = dA * inv_vn / fmaxf(sqrtf(nA), 1e-12f);
            sA = fminf(fmaxf(sA, 0.f), 1.f);
            float sB = dB * inv_vn / fmaxf(sqrtf(nB), 1e-12f);
            sB = fminf(fmaxf(sB, 0.f), 1.f);
            if (lane == 0) {
                float2 sv; sv.x = sA; sv.y = sB;      // r even -> 8B aligned
                *reinterpret_cast<float2*>(s_out + r) = sv;
            }
            esum += expf(sA) + expf(sB);
        }

        if (lane == 0) wsum[wib] = esum;
        __syncthreads();
        if (tid == 0) part[blockIdx.x] = (wsum[0] + wsum[1]) + (wsum[2] + wsum[3]);
    }

    // ---------------- boundary 1: release ticket ----------------
    __threadfence();
    __syncthreads();
    if (tid == 0)
        tksh = __hip_atomic_fetch_add(&counters[0], 1u,
                                      __ATOMIC_ACQ_REL, __HIP_MEMORY_SCOPE_AGENT);
    __syncthreads();
    const u32 t1 = tksh;
    if (t1 < (u32)(BLOCKS - TK_BLOCKS)) return;   // non-finisher blocks retire

    if (tid == 0) {
        while (__hip_atomic_load(&counters[0], __ATOMIC_ACQUIRE,
                                 __HIP_MEMORY_SCOPE_AGENT) < (u32)BLOCKS)
            __builtin_amdgcn_s_sleep(2);
    }
    __syncthreads();
    __threadfence();   // acquire: all phase-1 s_out/part now visible

    // ---------------- phase 2: chunk top-25 (wave 0 only) ----------------
    const int chunk = (int)t1 - (BLOCKS - TK_BLOCKS);
    if (wib == 0) {
        const int base = chunk * TK_CHUNK;
        u64 k[KPT];
        #pragma unroll
        for (int j = 0; j < KPT; ++j) {
            const int i = lane + 64 * j;
            u64 key = 0ull;
            if (i < TK_CHUNK) {
                const int g = base + i;
                if (g < N)
                    key = ((u64)__float_as_uint(s_out[g]) << 32) |
                          (u64)(0xFFFFFFFFu - (u32)g);
            }
            k[j] = key;
        }
        for (int r = 0; r < TOPK; ++r) {
            u64 m = k[0];
            #pragma unroll
            for (int j = 1; j < KPT; ++j) m = (k[j] > m) ? k[j] : m;
            u64 w = m;
            #pragma unroll
            for (int off = 32; off; off >>= 1) {
                const u64 ow = __shfl_xor(w, off);
                w = (ow > w) ? ow : w;
            }
            if (lane == 0) cand[chunk * TOPK + r] = w;
            #pragma unroll
            for (int j = 0; j < KPT; ++j) if (k[j] == w) k[j] = 0ull;
        }
    }

    // ---------------- boundary 2 ----------------
    __threadfence();
    __syncthreads();
    if (tid == 0)
        tksh = __hip_atomic_fetch_add(&counters[1], 1u,
                                      __ATOMIC_ACQ_REL, __HIP_MEMORY_SCOPE_AGENT);
    __syncthreads();
    if (tksh != (u32)(TK_BLOCKS - 1)) return;     // only the last finisher stays
    __threadfence();                              // all cand[] visible

    // ---------------- phase 3: Z, merge, oia, out (256 threads) ----------
    // (a) softmax denominator Z (power-of-2 deterministic tree)
    float z = 0.f;
    for (int i = tid; i < BLOCKS; i += 256) z += part[i];
    red[tid] = z;
    __syncthreads();
    for (int s = 128; s > 0; s >>= 1) {
        if (tid < s) red[tid] += red[tid + s];
        __syncthreads();
    }
    if (tid == 0) zsh = red[0];

    // stage candidates in LDS
    for (int i = tid; i < NCAND; i += 256) ck[i] = cand[i];
    __syncthreads();

    // (b) 64-way sorted-list merge on wave 0 (wave-synchronous)
    if (wib == 0) {
        int cur = 0;
        u64 head = ck[lane * TOPK];
        for (int r = 0; r < TOPK; ++r) {
            u64 w = head;
            #pragma unroll
            for (int off = 32; off; off >>= 1) {
                const u64 ow = __shfl_xor(w, off);
                w = (ow > w) ? ow : w;
            }
            if (lane == 0) {
                topw[r] = expf(__uint_as_float((u32)(w >> 32)));
                topi[r] = (int)(0xFFFFFFFFu - (u32)(w & 0xFFFFFFFFu));
            }
            if (head == w) {   // exactly one lane (keys unique)
                ++cur;
                head = (cur < TOPK) ? ck[lane * TOPK + cur] : 0ull;
            }
        }
    }
    __syncthreads();

    // (c) oia gather: attention_j = exp(s_j)/Z * vid_gate; vid_gate = 2*sigmoid(t)
    const float gate  = 2.f / (1.f + expf(-temp_vid[0]));
    const float scale = gate / zsh;
    for (int d = tid; d < OD; d += 256) {
        float acc = 0.f;
        #pragma unroll
        for (int j = 0; j < TOPK; ++j)
            acc = fmaf(topw[j] * scale, n_answ[(size_t)topi[j] * OD + d], acc);
        oiash[d] = acc;
    }
    __syncthreads();

    // (d) 3 dot products
    for (int kk = 0; kk < 3; ++kk) {
        float a = 0.f;
        for (int d = tid; d < OD; d += 256)
            a = fmaf(oiash[d], o[kk * OD + d], a);
        red[tid] = a;
        __syncthreads();
        for (int s = 128; s > 0; s >>= 1) {
            if (tid < s) red[tid] += red[tid + s];
            __syncthreads();
        }
        if (tid == 0) out[kk] = red[0];
        __syncthreads();
    }
}

// ---------------------------------------------------------------------------
extern "C" void kernel_launch(void* const* d_in, const int* in_sizes, int n_in,
                              void* d_out, int out_size, void* d_ws, size_t ws_size,
                              hipStream_t stream)
{
    // setup_inputs order:
    // 0 v, 1 n_feats, 2 aud, 3 n_auds, 4 ocr, 5 n_ocrs, 6 o, 7 n_answ,
    // 8 temp_vid, 9 temp_aud, 10 temp_ocr
    const float* v        = (const float*)d_in[0];
    const float* n_feats  = (const float*)d_in[1];
    const float* o        = (const float*)d_in[6];
    const float* n_answ   = (const float*)d_in[7];
    const float* temp_vid = (const float*)d_in[8];
    // aud/ocr branches are multiplied by exactly 0.0 in the reference -> skipped.
    float* out = (float*)d_out;

    char* ws = (char*)d_ws;
    u32*   counters = (u32*)ws;                 // 8 B, zeroed per call below
    float* ws_s     = (float*)(ws + 256);       // 50000 f32 = 200000 B
    float* ws_part  = (float*)(ws + 200704);    // 2048 f32  = 8192 B
    u64*   ws_cand  = (u64*)  (ws + 208896);    // 1600 u64  = 12800 B

    hipMemsetAsync(counters, 0, 8, stream);     // async, graph-capturable
    k_fused<<<BLOCKS, THREADS, 0, stream>>>(v, n_feats, n_answ, o, temp_vid,
                                            counters, ws_s, ws_part, ws_cand, out);
}

// Round 5
// 129.118 us; speedup vs baseline: 2.7705x; 2.7705x over previous
//
#include <hip/hip_runtime.h>
#include <cstdint>
#include <cstddef>

typedef unsigned long long u64;
typedef unsigned int u32;

// Problem constants (from reference)
constexpr int N    = 50000;   // library size
constexpr int D    = 768;     // vision dim
constexpr int OD   = 384;     // option / answer dim
constexpr int TOPK = 25;

// K1 config: one 64-lane wave per row-pair
constexpr int K1_BLOCKS  = 2048;
constexpr int K1_THREADS = 256;                            // 4 waves
constexpr int WAVES_TOTAL = K1_BLOCKS * (K1_THREADS / 64); // 8192

// top-k config: 64 chunks, processed by 16 waves of ONE block (4 chunks/wave)
constexpr int TK_CHUNKS = 64;
constexpr int TK_CHUNK  = 782;               // 64*782 = 50048 >= 50000
constexpr int KPT       = 13;                // 64*13 = 832 >= 782
constexpr int NCAND     = TK_CHUNKS * TOPK;  // 1600

// ---------------------------------------------------------------------------
// K1: per-row cosine score s[n] = clip(dot(v,f_n)/(|v||f_n|), 0, 1),
//     plus per-block partial sums of exp(s[n]) (softmax denominator).
// One wave per TWO rows per iteration; proven in round 3 (absmax 0.0).
// No atomics / fences: cross-kernel visibility is handled by the kernel
// boundary (ONE L2 flush, vs per-block flushes that cost 8x in round 4).
// ---------------------------------------------------------------------------
__global__ __launch_bounds__(K1_THREADS)
void k_scores(const float* __restrict__ v,
              const float* __restrict__ n_feats,
              float* __restrict__ s_out,
              float* __restrict__ part_out)
{
    const int lane  = threadIdx.x & 63;
    const int wib   = threadIdx.x >> 6;           // wave in block (0..3)
    const int gwave = blockIdx.x * 4 + wib;       // global wave id

    const float4* v4 = reinterpret_cast<const float4*>(v);
    const float4 va = v4[lane];
    const float4 vb = v4[lane + 64];
    const float4 vc = v4[lane + 128];

    float vsq = 0.f;
    vsq = fmaf(va.x, va.x, vsq); vsq = fmaf(va.y, va.y, vsq);
    vsq = fmaf(va.z, va.z, vsq); vsq = fmaf(va.w, va.w, vsq);
    vsq = fmaf(vb.x, vb.x, vsq); vsq = fmaf(vb.y, vb.y, vsq);
    vsq = fmaf(vb.z, vb.z, vsq); vsq = fmaf(vb.w, vb.w, vsq);
    vsq = fmaf(vc.x, vc.x, vsq); vsq = fmaf(vc.y, vc.y, vsq);
    vsq = fmaf(vc.z, vc.z, vsq); vsq = fmaf(vc.w, vc.w, vsq);
    #pragma unroll
    for (int off = 32; off; off >>= 1) vsq += __shfl_xor(vsq, off);
    const float inv_vn = 1.0f / fmaxf(sqrtf(vsq), 1e-12f);

    float esum = 0.f;
    for (int r = 2 * gwave; r < N; r += 2 * WAVES_TOTAL) {
        // N is even: r+1 < N always
        const float4* f0 = reinterpret_cast<const float4*>(n_feats + (size_t)r * D);
        const float4* f1 = reinterpret_cast<const float4*>(n_feats + (size_t)(r + 1) * D);
        const float4 a0 = f0[lane];
        const float4 a1 = f0[lane + 64];
        const float4 a2 = f0[lane + 128];
        const float4 b0 = f1[lane];
        const float4 b1 = f1[lane + 64];
        const float4 b2 = f1[lane + 128];

        float dA = 0.f, nA = 0.f, dB = 0.f, nB = 0.f;
        dA = fmaf(a0.x, va.x, dA); nA = fmaf(a0.x, a0.x, nA);
        dB = fmaf(b0.x, va.x, dB); nB = fmaf(b0.x, b0.x, nB);
        dA = fmaf(a0.y, va.y, dA); nA = fmaf(a0.y, a0.y, nA);
        dB = fmaf(b0.y, va.y, dB); nB = fmaf(b0.y, b0.y, nB);
        dA = fmaf(a0.z, va.z, dA); nA = fmaf(a0.z, a0.z, nA);
        dB = fmaf(b0.z, va.z, dB); nB = fmaf(b0.z, b0.z, nB);
        dA = fmaf(a0.w, va.w, dA); nA = fmaf(a0.w, a0.w, nA);
        dB = fmaf(b0.w, va.w, dB); nB = fmaf(b0.w, b0.w, nB);
        dA = fmaf(a1.x, vb.x, dA); nA = fmaf(a1.x, a1.x, nA);
        dB = fmaf(b1.x, vb.x, dB); nB = fmaf(b1.x, b1.x, nB);
        dA = fmaf(a1.y, vb.y, dA); nA = fmaf(a1.y, a1.y, nA);
        dB = fmaf(b1.y, vb.y, dB); nB = fmaf(b1.y, b1.y, nB);
        dA = fmaf(a1.z, vb.z, dA); nA = fmaf(a1.z, a1.z, nA);
        dB = fmaf(b1.z, vb.z, dB); nB = fmaf(b1.z, b1.z, nB);
        dA = fmaf(a1.w, vb.w, dA); nA = fmaf(a1.w, a1.w, nA);
        dB = fmaf(b1.w, vb.w, dB); nB = fmaf(b1.w, b1.w, nB);
        dA = fmaf(a2.x, vc.x, dA); nA = fmaf(a2.x, a2.x, nA);
        dB = fmaf(b2.x, vc.x, dB); nB = fmaf(b2.x, b2.x, nB);
        dA = fmaf(a2.y, vc.y, dA); nA = fmaf(a2.y, a2.y, nA);
        dB = fmaf(b2.y, vc.y, dB); nB = fmaf(b2.y, b2.y, nB);
        dA = fmaf(a2.z, vc.z, dA); nA = fmaf(a2.z, a2.z, nA);
        dB = fmaf(b2.z, vc.z, dB); nB = fmaf(b2.z, b2.z, nB);
        dA = fmaf(a2.w, vc.w, dA); nA = fmaf(a2.w, a2.w, nA);
        dB = fmaf(b2.w, vc.w, dB); nB = fmaf(b2.w, b2.w, nB);

        #pragma unroll
        for (int off = 32; off; off >>= 1) {
            dA += __shfl_xor(dA, off);
            nA += __shfl_xor(nA, off);
            dB += __shfl_xor(dB, off);
            nB += __shfl_xor(nB, off);
        }

        float sA = dA * inv_vn / fmaxf(sqrtf(nA), 1e-12f);
        sA = fminf(fmaxf(sA, 0.f), 1.f);
        float sB = dB * inv_vn / fmaxf(sqrtf(nB), 1e-12f);
        sB = fminf(fmaxf(sB, 0.f), 1.f);
        if (lane == 0) {
            float2 sv; sv.x = sA; sv.y = sB;      // r even -> 8B aligned
            *reinterpret_cast<float2*>(s_out + r) = sv;
        }
        esum += expf(sA) + expf(sB);
    }

    __shared__ float wsum[4];
    if (lane == 0) wsum[wib] = esum;
    __syncthreads();
    if (threadIdx.x == 0)
        part_out[blockIdx.x] = (wsum[0] + wsum[1]) + (wsum[2] + wsum[3]);
}

// ---------------------------------------------------------------------------
// K2: ONE block, 1024 threads (16 waves). Fuses the old K2+K3 (no cross-block
// dependency -> no atomics needed):
//  (a) Z = sum of 2048 exp-partials (power-of-2 LDS tree, deterministic)
//  (b) each wave computes exact top-25 of 4 chunks (keys in registers,
//      wave-synchronous, results straight to LDS — proven round-3 math)
//  (c) wave-0 64-way sorted-list merge -> global top-25
//  (d) oia[d] = sum_j w_j * n_answ[idx_j][d];  scores[k] = dot(oia, o[k])
// Key = (value_bits<<32)|(~idx): larger value wins, ties -> lower index
// (matches jax.lax.top_k); s >= 0 so float bits are integer-ordered.
// ---------------------------------------------------------------------------
__global__ __launch_bounds__(1024)
void k_finish(const float* __restrict__ s_in,
              const float* __restrict__ part,
              const float* __restrict__ n_answ,
              const float* __restrict__ o,
              const float* __restrict__ temp_vid,
              float* __restrict__ out)
{
    __shared__ u64   ck[NCAND];      // 12.8 KB
    __shared__ float red[1024];
    __shared__ float oiash[OD];
    __shared__ float topw[TOPK];
    __shared__ int   topi[TOPK];
    __shared__ float zsh;

    const int tid  = threadIdx.x;
    const int lane = tid & 63;
    const int wv   = tid >> 6;       // 0..15

    // (a) softmax denominator Z over part[2048] (2048 = 2*1024 exactly)
    red[tid] = part[tid] + part[tid + 1024];
    __syncthreads();
    for (int s = 512; s > 0; s >>= 1) {
        if (tid < s) red[tid] += red[tid + s];
        __syncthreads();
    }
    if (tid == 0) zsh = red[0];
    // (visibility of zsh to all threads is ordered by the barrier after (b))

    // (b) per-chunk exact top-25; wave wv handles chunks wv, wv+16, wv+32, wv+48
    for (int c = wv; c < TK_CHUNKS; c += 16) {
        const int base = c * TK_CHUNK;
        u64 k[KPT];
        #pragma unroll
        for (int j = 0; j < KPT; ++j) {
            const int i = lane + 64 * j;
            u64 key = 0ull;
            if (i < TK_CHUNK) {
                const int g = base + i;
                if (g < N)
                    key = ((u64)__float_as_uint(s_in[g]) << 32) |
                          (u64)(0xFFFFFFFFu - (u32)g);
            }
            k[j] = key;
        }
        for (int r = 0; r < TOPK; ++r) {
            u64 m = k[0];
            #pragma unroll
            for (int j = 1; j < KPT; ++j) m = (k[j] > m) ? k[j] : m;
            u64 w = m;
            #pragma unroll
            for (int off = 32; off; off >>= 1) {
                const u64 ow = __shfl_xor(w, off);
                w = (ow > w) ? ow : w;
            }
            if (lane == 0) ck[c * TOPK + r] = w;
            #pragma unroll
            for (int j = 0; j < KPT; ++j) if (k[j] == w) k[j] = 0ull;  // unique keys
        }
    }
    __syncthreads();

    // (c) 64-way sorted-list merge on wave 0 (wave-synchronous)
    if (wv == 0) {
        int cur = 0;
        u64 head = ck[lane * TOPK];   // every chunk has >=25 real keys
        for (int r = 0; r < TOPK; ++r) {
            u64 w = head;
            #pragma unroll
            for (int off = 32; off; off >>= 1) {
                const u64 ow = __shfl_xor(w, off);
                w = (ow > w) ? ow : w;
            }
            if (lane == 0) {
                topw[r] = expf(__uint_as_float((u32)(w >> 32)));
                topi[r] = (int)(0xFFFFFFFFu - (u32)(w & 0xFFFFFFFFu));
            }
            if (head == w) {          // exactly one lane advances
                ++cur;
                head = (cur < TOPK) ? ck[lane * TOPK + cur] : 0ull;
            }
        }
    }
    __syncthreads();

    // (d) oia gather + 3 dots.  attention_j = exp(s_j)/Z * 2*sigmoid(temp)
    const float gate  = 2.f / (1.f + expf(-temp_vid[0]));
    const float scale = gate / zsh;
    if (tid < OD) {
        float acc = 0.f;
        #pragma unroll
        for (int j = 0; j < TOPK; ++j)
            acc = fmaf(topw[j] * scale, n_answ[(size_t)topi[j] * OD + tid], acc);
        oiash[tid] = acc;
    }
    __syncthreads();

    for (int kk = 0; kk < 3; ++kk) {
        red[tid] = (tid < OD) ? oiash[tid] * o[kk * OD + tid] : 0.f;
        __syncthreads();
        for (int s = 512; s > 0; s >>= 1) {
            if (tid < s) red[tid] += red[tid + s];
            __syncthreads();
        }
        if (tid == 0) out[kk] = red[0];
        __syncthreads();
    }
}

// ---------------------------------------------------------------------------
extern "C" void kernel_launch(void* const* d_in, const int* in_sizes, int n_in,
                              void* d_out, int out_size, void* d_ws, size_t ws_size,
                              hipStream_t stream)
{
    // setup_inputs order:
    // 0 v, 1 n_feats, 2 aud, 3 n_auds, 4 ocr, 5 n_ocrs, 6 o, 7 n_answ,
    // 8 temp_vid, 9 temp_aud, 10 temp_ocr
    const float* v        = (const float*)d_in[0];
    const float* n_feats  = (const float*)d_in[1];
    const float* o        = (const float*)d_in[6];
    const float* n_answ   = (const float*)d_in[7];
    const float* temp_vid = (const float*)d_in[8];
    // aud/ocr branches are multiplied by exactly 0.0 in the reference -> skipped.
    float* out = (float*)d_out;

    char* ws = (char*)d_ws;
    float* ws_s    = (float*)(ws);           // 50000 f32 = 200000 B
    float* ws_part = (float*)(ws + 200704);  // 2048 f32  = 8192 B

    k_scores<<<K1_BLOCKS, K1_THREADS, 0, stream>>>(v, n_feats, ws_s, ws_part);
    k_finish<<<1, 1024, 0, stream>>>(ws_s, ws_part, n_answ, o, temp_vid, out);
}

// Round 6
// 70.003 us; speedup vs baseline: 5.1100x; 1.8445x over previous
//
#include <hip/hip_runtime.h>
#include <cstdint>
#include <cstddef>

typedef unsigned long long u64;
typedef unsigned int u32;

// Problem constants (from reference)
constexpr int N    = 50000;   // library size
constexpr int NPAD = 50176;   // 49 * 1024, uniform trip count for 1024 threads
constexpr int D    = 768;     // vision dim
constexpr int OD   = 384;     // option / answer dim
constexpr int TOPK = 25;

// K1 config: one 64-lane wave per row-pair (proven at HBM floor, round 3/5)
constexpr int K1_BLOCKS  = 2048;
constexpr int K1_THREADS = 256;                            // 4 waves
constexpr int WAVES_TOTAL = K1_BLOCKS * (K1_THREADS / 64); // 8192

// ---------------------------------------------------------------------------
// K1: per-row cosine score s[n] = clip(dot(v,f_n)/(|v||f_n|), 0, 1),
//     plus per-block partial sums of exp(s[n]) (softmax denominator).
// UNCHANGED from round 3/5: measured at the 153.6MB HBM floor (~25 us).
// ---------------------------------------------------------------------------
__global__ __launch_bounds__(K1_THREADS)
void k_scores(const float* __restrict__ v,
              const float* __restrict__ n_feats,
              float* __restrict__ s_out,
              float* __restrict__ part_out)
{
    const int lane  = threadIdx.x & 63;
    const int wib   = threadIdx.x >> 6;           // wave in block (0..3)
    const int gwave = blockIdx.x * 4 + wib;       // global wave id

    const float4* v4 = reinterpret_cast<const float4*>(v);
    const float4 va = v4[lane];
    const float4 vb = v4[lane + 64];
    const float4 vc = v4[lane + 128];

    float vsq = 0.f;
    vsq = fmaf(va.x, va.x, vsq); vsq = fmaf(va.y, va.y, vsq);
    vsq = fmaf(va.z, va.z, vsq); vsq = fmaf(va.w, va.w, vsq);
    vsq = fmaf(vb.x, vb.x, vsq); vsq = fmaf(vb.y, vb.y, vsq);
    vsq = fmaf(vb.z, vb.z, vsq); vsq = fmaf(vb.w, vb.w, vsq);
    vsq = fmaf(vc.x, vc.x, vsq); vsq = fmaf(vc.y, vc.y, vsq);
    vsq = fmaf(vc.w, vc.w, vsq); vsq = fmaf(vc.z, vc.z, vsq);
    #pragma unroll
    for (int off = 32; off; off >>= 1) vsq += __shfl_xor(vsq, off);
    const float inv_vn = 1.0f / fmaxf(sqrtf(vsq), 1e-12f);

    float esum = 0.f;
    for (int r = 2 * gwave; r < N; r += 2 * WAVES_TOTAL) {
        // N is even: r+1 < N always
        const float4* f0 = reinterpret_cast<const float4*>(n_feats + (size_t)r * D);
        const float4* f1 = reinterpret_cast<const float4*>(n_feats + (size_t)(r + 1) * D);
        const float4 a0 = f0[lane];
        const float4 a1 = f0[lane + 64];
        const float4 a2 = f0[lane + 128];
        const float4 b0 = f1[lane];
        const float4 b1 = f1[lane + 64];
        const float4 b2 = f1[lane + 128];

        float dA = 0.f, nA = 0.f, dB = 0.f, nB = 0.f;
        dA = fmaf(a0.x, va.x, dA); nA = fmaf(a0.x, a0.x, nA);
        dB = fmaf(b0.x, va.x, dB); nB = fmaf(b0.x, b0.x, nB);
        dA = fmaf(a0.y, va.y, dA); nA = fmaf(a0.y, a0.y, nA);
        dB = fmaf(b0.y, va.y, dB); nB = fmaf(b0.y, b0.y, nB);
        dA = fmaf(a0.z, va.z, dA); nA = fmaf(a0.z, a0.z, nA);
        dB = fmaf(b0.z, va.z, dB); nB = fmaf(b0.z, b0.z, nB);
        dA = fmaf(a0.w, va.w, dA); nA = fmaf(a0.w, a0.w, nA);
        dB = fmaf(b0.w, va.w, dB); nB = fmaf(b0.w, b0.w, nB);
        dA = fmaf(a1.x, vb.x, dA); nA = fmaf(a1.x, a1.x, nA);
        dB = fmaf(b1.x, vb.x, dB); nB = fmaf(b1.x, b1.x, nB);
        dA = fmaf(a1.y, vb.y, dA); nA = fmaf(a1.y, a1.y, nA);
        dB = fmaf(b1.y, vb.y, dB); nB = fmaf(b1.y, b1.y, nB);
        dA = fmaf(a1.z, vb.z, dA); nA = fmaf(a1.z, a1.z, nA);
        dB = fmaf(b1.z, vb.z, dB); nB = fmaf(b1.z, b1.z, nB);
        dA = fmaf(a1.w, vb.w, dA); nA = fmaf(a1.w, a1.w, nA);
        dB = fmaf(b1.w, vb.w, dB); nB = fmaf(b1.w, b1.w, nB);
        dA = fmaf(a2.x, vc.x, dA); nA = fmaf(a2.x, a2.x, nA);
        dB = fmaf(b2.x, vc.x, dB); nB = fmaf(b2.x, b2.x, nB);
        dA = fmaf(a2.y, vc.y, dA); nA = fmaf(a2.y, a2.y, nA);
        dB = fmaf(b2.y, vc.y, dB); nB = fmaf(b2.y, b2.y, nB);
        dA = fmaf(a2.z, vc.z, dA); nA = fmaf(a2.z, a2.z, nA);
        dB = fmaf(b2.z, vc.z, dB); nB = fmaf(b2.z, b2.z, nB);
        dA = fmaf(a2.w, vc.w, dA); nA = fmaf(a2.w, a2.w, nA);
        dB = fmaf(b2.w, vc.w, dB); nB = fmaf(b2.w, b2.w, nB);

        #pragma unroll
        for (int off = 32; off; off >>= 1) {
            dA += __shfl_xor(dA, off);
            nA += __shfl_xor(nA, off);
            dB += __shfl_xor(dB, off);
            nB += __shfl_xor(nB, off);
        }

        float sA = dA * inv_vn / fmaxf(sqrtf(nA), 1e-12f);
        sA = fminf(fmaxf(sA, 0.f), 1.f);
        float sB = dB * inv_vn / fmaxf(sqrtf(nB), 1e-12f);
        sB = fminf(fmaxf(sB, 0.f), 1.f);
        if (lane == 0) {
            float2 sv; sv.x = sA; sv.y = sB;      // r even -> 8B aligned
            *reinterpret_cast<float2*>(s_out + r) = sv;
        }
        esum += expf(sA) + expf(sB);
    }

    __shared__ float wsum[4];
    if (lane == 0) wsum[wib] = esum;
    __syncthreads();
    if (threadIdx.x == 0)
        part_out[blockIdx.x] = (wsum[0] + wsum[1]) + (wsum[2] + wsum[3]);
}

// ---------------------------------------------------------------------------
// K2: ONE block, 1024 threads. Top-25 via two-level histogram radix-select
// (throughput-bound scans, NO serial extraction rounds — round 5's 104us
// k_finish was 25 serial butterfly rounds of ~1us latency each).
//  (a) Z = sum of 2048 exp-partials (power-of-2 LDS tree)
//  (b) level-1 histogram of float bits>>20 (monotone on s in [0,1]); zeros
//      (~50% of data, clip) counted via per-wave ballot+popc, not atomics
//  (c) 10-step Hillis-Steele suffix scan -> crossing bin b1 (cum count >= 25)
//  (d) level-2 histogram of bits 19..10 within bin b1 -> crossing bin b2
//  (e) compact: definite-top keys (<25) -> A; crossing-bin keys -> B;
//      bitonic-sort B desc; top-25 = A  U  B[0..needB)
//      key = (valbits<<32)|(~idx): value desc, ties -> lower index (jax)
//  (f) oia gather + 3 dots
// ---------------------------------------------------------------------------
__global__ __launch_bounds__(1024)
void k_finish(const float* __restrict__ s_in,
              const float* __restrict__ part,
              const float* __restrict__ n_answ,
              const float* __restrict__ o,
              const float* __restrict__ temp_vid,
              float* __restrict__ out)
{
    __shared__ u32   hist[1024];
    __shared__ u32   suf[1024];
    __shared__ float red[1024];
    __shared__ u64   Bl[4096];       // 32 KB candidate list
    __shared__ u64   Al[32];         // definite-top list (<25)
    __shared__ float oiash[OD];
    __shared__ float topw[TOPK];
    __shared__ int   topi[TOPK];
    __shared__ u32   ctrA, ctrB;
    __shared__ int   b1sh, b2sh;
    __shared__ float zsh;

    const int tid  = threadIdx.x;
    const int lane = tid & 63;

    // (a) Z over part[2048]
    red[tid]  = part[tid] + part[tid + 1024];
    hist[tid] = 0;
    if (tid == 0) { ctrA = 0; ctrB = 0; }
    __syncthreads();
    for (int s = 512; s > 0; s >>= 1) {
        if (tid < s) red[tid] += red[tid + s];
        __syncthreads();
    }
    if (tid == 0) zsh = red[0];

    // (b) level-1 histogram (uniform 49-trip loop; ballot fast-path for 0.0)
    u32 zc = 0;
    for (int i = tid; i < NPAD; i += 1024) {
        const bool in = i < N;
        const u32 vb = in ? __float_as_uint(s_in[i]) : 0u;
        const u64 zm = __ballot(in && vb == 0u);
        if (lane == 0) zc += (u32)__popcll(zm);
        if (in && vb != 0u) atomicAdd(&hist[vb >> 20], 1u);
    }
    if (lane == 0 && zc) atomicAdd(&hist[0], zc);
    __syncthreads();

    // (c) suffix scan level 1: suf[i] = #scores with bin >= i
    suf[tid] = hist[tid];
    __syncthreads();
    for (int s = 1; s < 1024; s <<= 1) {
        const u32 add = (tid + s < 1024) ? suf[tid + s] : 0u;
        __syncthreads();
        suf[tid] += add;
        __syncthreads();
    }
    if (suf[tid] >= (u32)TOPK && (tid == 1023 || suf[tid + 1] < (u32)TOPK))
        b1sh = tid;                                  // exactly one thread
    __syncthreads();
    const int b1        = b1sh;
    const u32 cntAbove1 = (b1 < 1023) ? suf[b1 + 1] : 0u;   // < 25
    const u32 need1     = (u32)TOPK - cntAbove1;            // in [1,25]
    __syncthreads();
    hist[tid] = 0;
    __syncthreads();

    // (d) level-2 histogram within coarse bin b1 (bits 19..10)
    for (int i = tid; i < N; i += 1024) {
        const u32 vb = __float_as_uint(s_in[i]);
        if ((int)(vb >> 20) == b1) atomicAdd(&hist[(vb >> 10) & 1023u], 1u);
    }
    __syncthreads();
    suf[tid] = hist[tid];
    __syncthreads();
    for (int s = 1; s < 1024; s <<= 1) {
        const u32 add = (tid + s < 1024) ? suf[tid + s] : 0u;
        __syncthreads();
        suf[tid] += add;
        __syncthreads();
    }
    if (suf[tid] >= need1 && (tid == 1023 || suf[tid + 1] < need1))
        b2sh = tid;
    __syncthreads();
    const int b2        = b2sh;
    const u32 cntAbove2 = (b2 < 1023) ? suf[b2 + 1] : 0u;
    const u32 cntA      = cntAbove1 + cntAbove2;     // < 25
    const u32 needB     = (u32)TOPK - cntA;          // >= 1

    // (e) compact A (definite top) and B (crossing fine bin)
    for (int i = tid; i < N; i += 1024) {
        const u32 vb = __float_as_uint(s_in[i]);
        const int cb = (int)(vb >> 20);
        if (cb < b1) continue;
        const int fb = (int)((vb >> 10) & 1023u);
        const u64 key = ((u64)vb << 32) | (u64)(0xFFFFFFFFu - (u32)i);
        if (cb > b1 || fb > b2) {
            const u32 p = atomicAdd(&ctrA, 1u);
            Al[p] = key;
        } else if (fb == b2) {
            const u32 p = atomicAdd(&ctrB, 1u);
            if (p < 4096u) Bl[p] = key;              // cap (pathological only)
        }
    }
    __syncthreads();

    const u32 nB = (ctrB < 4096u) ? ctrB : 4096u;
    u32 P = 2; while (P < nB) P <<= 1;
    for (int i = (int)nB + tid; i < (int)P; i += 1024) Bl[i] = 0ull; // pad (real keys > 0)
    __syncthreads();
    // bitonic sort, descending (largest key at index 0)
    for (u32 k = 2; k <= P; k <<= 1) {
        for (u32 j = k >> 1; j > 0; j >>= 1) {
            for (u32 i = tid; i < P; i += 1024) {
                const u32 ixj = i ^ j;
                if (ixj > i) {
                    const u64 a = Bl[i], c = Bl[ixj];
                    const bool up = ((i & k) == 0);
                    if (up ? (a < c) : (a > c)) { Bl[i] = c; Bl[ixj] = a; }
                }
            }
            __syncthreads();
        }
    }

    // top-25 = Al[0..cntA) U Bl[0..needB)
    if (tid < TOPK) {
        const u64 kk = (tid < (int)cntA) ? Al[tid] : Bl[tid - (int)cntA];
        topw[tid] = expf(__uint_as_float((u32)(kk >> 32)));
        topi[tid] = (int)(0xFFFFFFFFu - (u32)(kk & 0xFFFFFFFFu));
    }
    __syncthreads();

    // (f) oia gather + 3 dots.  attention_j = exp(s_j)/Z * 2*sigmoid(temp)
    const float gate  = 2.f / (1.f + expf(-temp_vid[0]));
    const float scale = gate / zsh;
    if (tid < OD) {
        float acc = 0.f;
        #pragma unroll
        for (int j = 0; j < TOPK; ++j)
            acc = fmaf(topw[j] * scale, n_answ[(size_t)topi[j] * OD + tid], acc);
        oiash[tid] = acc;
    }
    __syncthreads();

    for (int kk2 = 0; kk2 < 3; ++kk2) {
        red[tid] = (tid < OD) ? oiash[tid] * o[kk2 * OD + tid] : 0.f;
        __syncthreads();
        for (int s = 512; s > 0; s >>= 1) {
            if (tid < s) red[tid] += red[tid + s];
            __syncthreads();
        }
        if (tid == 0) out[kk2] = red[0];
        __syncthreads();
    }
}

// ---------------------------------------------------------------------------
extern "C" void kernel_launch(void* const* d_in, const int* in_sizes, int n_in,
                              void* d_out, int out_size, void* d_ws, size_t ws_size,
                              hipStream_t stream)
{
    // setup_inputs order:
    // 0 v, 1 n_feats, 2 aud, 3 n_auds, 4 ocr, 5 n_ocrs, 6 o, 7 n_answ,
    // 8 temp_vid, 9 temp_aud, 10 temp_ocr
    const float* v        = (const float*)d_in[0];
    const float* n_feats  = (const float*)d_in[1];
    const float* o        = (const float*)d_in[6];
    const float* n_answ   = (const float*)d_in[7];
    const float* temp_vid = (const float*)d_in[8];
    // aud/ocr branches are multiplied by exactly 0.0 in the reference -> skipped.
    float* out = (float*)d_out;

    char* ws = (char*)d_ws;
    float* ws_s    = (float*)(ws);           // 50000 f32 = 200000 B
    float* ws_part = (float*)(ws + 200704);  // 2048 f32  = 8192 B

    k_scores<<<K1_BLOCKS, K1_THREADS, 0, stream>>>(v, n_feats, ws_s, ws_part);
    k_finish<<<1, 1024, 0, stream>>>(ws_s, ws_part, n_answ, o, temp_vid, out);
}

// Round 8
// 41.627 us; speedup vs baseline: 8.5933x; 1.6817x over previous
//
#include <hip/hip_runtime.h>
#include <cstdint>
#include <cstddef>

typedef unsigned long long u64;
typedef unsigned int u32;

// Problem constants (from reference)
constexpr int N    = 50000;   // library size
constexpr int D    = 768;     // vision dim
constexpr int OD   = 384;     // option / answer dim
constexpr int TOPK = 25;

// K1 config: one 64-lane wave per row-pair (proven at HBM floor, rounds 3/5/6)
constexpr int K1_BLOCKS  = 2048;
constexpr int K1_THREADS = 256;                            // 4 waves
constexpr int WAVES_TOTAL = K1_BLOCKS * (K1_THREADS / 64); // 8192

// k_finish pass geometry: 50000 f32 = 12500 float4; 12*1024 burst + 212 tail
constexpr int N4    = 12500;
constexpr int BURST = 12;
constexpr int TAIL4 = N4 - BURST * 1024;   // 212
constexpr int CAP   = 4096;

// Histogram bin: float bits >> 20. s in [0,1] -> bits <= 0x3F800000 ->
// bin <= 0x3F8 = 1016 < 1024.  (Round-7 bug: >>18 gives 4064 -> OOB LDS.)
constexpr int BINSHIFT = 20;

// ---------------------------------------------------------------------------
// K1: per-row cosine score s[n] = clip(dot(v,f_n)/(|v||f_n|), 0, 1),
//     plus per-block partial sums of exp(s[n]) (softmax denominator).
// UNCHANGED (measured at the 153.6MB HBM floor, ~25 us).
// ---------------------------------------------------------------------------
__global__ __launch_bounds__(K1_THREADS)
void k_scores(const float* __restrict__ v,
              const float* __restrict__ n_feats,
              float* __restrict__ s_out,
              float* __restrict__ part_out)
{
    const int lane  = threadIdx.x & 63;
    const int wib   = threadIdx.x >> 6;           // wave in block (0..3)
    const int gwave = blockIdx.x * 4 + wib;       // global wave id

    const float4* v4 = reinterpret_cast<const float4*>(v);
    const float4 va = v4[lane];
    const float4 vb = v4[lane + 64];
    const float4 vc = v4[lane + 128];

    float vsq = 0.f;
    vsq = fmaf(va.x, va.x, vsq); vsq = fmaf(va.y, va.y, vsq);
    vsq = fmaf(va.z, va.z, vsq); vsq = fmaf(va.w, va.w, vsq);
    vsq = fmaf(vb.x, vb.x, vsq); vsq = fmaf(vb.y, vb.y, vsq);
    vsq = fmaf(vb.z, vb.z, vsq); vsq = fmaf(vb.w, vb.w, vsq);
    vsq = fmaf(vc.x, vc.x, vsq); vsq = fmaf(vc.y, vc.y, vsq);
    vsq = fmaf(vc.w, vc.w, vsq); vsq = fmaf(vc.z, vc.z, vsq);
    #pragma unroll
    for (int off = 32; off; off >>= 1) vsq += __shfl_xor(vsq, off);
    const float inv_vn = 1.0f / fmaxf(sqrtf(vsq), 1e-12f);

    float esum = 0.f;
    for (int r = 2 * gwave; r < N; r += 2 * WAVES_TOTAL) {
        // N is even: r+1 < N always
        const float4* f0 = reinterpret_cast<const float4*>(n_feats + (size_t)r * D);
        const float4* f1 = reinterpret_cast<const float4*>(n_feats + (size_t)(r + 1) * D);
        const float4 a0 = f0[lane];
        const float4 a1 = f0[lane + 64];
        const float4 a2 = f0[lane + 128];
        const float4 b0 = f1[lane];
        const float4 b1 = f1[lane + 64];
        const float4 b2 = f1[lane + 128];

        float dA = 0.f, nA = 0.f, dB = 0.f, nB = 0.f;
        dA = fmaf(a0.x, va.x, dA); nA = fmaf(a0.x, a0.x, nA);
        dB = fmaf(b0.x, va.x, dB); nB = fmaf(b0.x, b0.x, nB);
        dA = fmaf(a0.y, va.y, dA); nA = fmaf(a0.y, a0.y, nA);
        dB = fmaf(b0.y, va.y, dB); nB = fmaf(b0.y, b0.y, nB);
        dA = fmaf(a0.z, va.z, dA); nA = fmaf(a0.z, a0.z, nA);
        dB = fmaf(b0.z, va.z, dB); nB = fmaf(b0.z, b0.z, nB);
        dA = fmaf(a0.w, va.w, dA); nA = fmaf(a0.w, a0.w, nA);
        dB = fmaf(b0.w, va.w, dB); nB = fmaf(b0.w, b0.w, nB);
        dA = fmaf(a1.x, vb.x, dA); nA = fmaf(a1.x, a1.x, nA);
        dB = fmaf(b1.x, vb.x, dB); nB = fmaf(b1.x, b1.x, nB);
        dA = fmaf(a1.y, vb.y, dA); nA = fmaf(a1.y, a1.y, nA);
        dB = fmaf(b1.y, vb.y, dB); nB = fmaf(b1.y, b1.y, nB);
        dA = fmaf(a1.z, vb.z, dA); nA = fmaf(a1.z, a1.z, nA);
        dB = fmaf(b1.z, vb.z, dB); nB = fmaf(b1.z, b1.z, nB);
        dA = fmaf(a1.w, vb.w, dA); nA = fmaf(a1.w, a1.w, nA);
        dB = fmaf(b1.w, vb.w, dB); nB = fmaf(b1.w, b1.w, nB);
        dA = fmaf(a2.x, vc.x, dA); nA = fmaf(a2.x, a2.x, nA);
        dB = fmaf(b2.x, vc.x, dB); nB = fmaf(b2.x, b2.x, nB);
        dA = fmaf(a2.y, vc.y, dA); nA = fmaf(a2.y, a2.y, nA);
        dB = fmaf(b2.y, vc.y, dB); nB = fmaf(b2.y, b2.y, nB);
        dA = fmaf(a2.z, vc.z, dA); nA = fmaf(a2.z, a2.z, nA);
        dB = fmaf(b2.z, vc.z, dB); nB = fmaf(b2.z, b2.z, nB);
        dA = fmaf(a2.w, vc.w, dA); nA = fmaf(a2.w, a2.w, nA);
        dB = fmaf(b2.w, vc.w, dB); nB = fmaf(b2.w, b2.w, nB);

        #pragma unroll
        for (int off = 32; off; off >>= 1) {
            dA += __shfl_xor(dA, off);
            nA += __shfl_xor(nA, off);
            dB += __shfl_xor(dB, off);
            nB += __shfl_xor(nB, off);
        }

        float sA = dA * inv_vn / fmaxf(sqrtf(nA), 1e-12f);
        sA = fminf(fmaxf(sA, 0.f), 1.f);
        float sB = dB * inv_vn / fmaxf(sqrtf(nB), 1e-12f);
        sB = fminf(fmaxf(sB, 0.f), 1.f);
        if (lane == 0) {
            float2 sv; sv.x = sA; sv.y = sB;      // r even -> 8B aligned
            *reinterpret_cast<float2*>(s_out + r) = sv;
        }
        esum += expf(sA) + expf(sB);
    }

    __shared__ float wsum[4];
    if (lane == 0) wsum[wib] = esum;
    __syncthreads();
    if (threadIdx.x == 0)
        part_out[blockIdx.x] = (wsum[0] + wsum[1]) + (wsum[2] + wsum[3]);
}

// ---------------------------------------------------------------------------
// K2: ONE block, 1024 threads. Latency-hidden radix-select:
//  (a) Z = sum of 2048 exp-partials
//  (b) pass 1 (12-deep float4 burst, ~200 KB in flight): 1024-bin histogram
//      of float bits>>20 (s<=1.0 -> bin<=1016). Zeros (clip) skipped —
//      assumes >=25 positive scores (~25000 here).
//  (c) ping-pong suffix scan -> crossing bin b1 (cum count >= 25)
//  (d) pass 2 (burst): compact ALL keys with bin >= b1 into L (expected
//      ~50, cap 4096). key = (valbits<<32)|(~idx): value desc, ties -> lower
//      index (matches jax.lax.top_k; only the top-25 SET matters anyway).
//  (e) rank-sort L via LDS broadcast reads -> exact top-25, deterministic.
//  (f) oia gather + 3 dots in one packed tree.
// ---------------------------------------------------------------------------
__global__ __launch_bounds__(1024)
void k_finish(const float4* __restrict__ s4,
              const float* __restrict__ part,
              const float* __restrict__ n_answ,
              const float* __restrict__ o,
              const float* __restrict__ temp_vid,
              float* __restrict__ out)
{
    __shared__ u32   hist[1024];
    __shared__ u32   sufb[1024];
    __shared__ float redA[1024], redB[1024], redC[1024];
    __shared__ u64   L[CAP];         // 32 KB
    __shared__ u64   Ls[TOPK];
    __shared__ float topw[TOPK];
    __shared__ int   topi[TOPK];
    __shared__ u32   ctrL;
    __shared__ int   b1sh;
    __shared__ float zsh;

    const int tid = threadIdx.x;

    // (a) Z over part[2048] (redA as scratch)
    redA[tid] = part[tid] + part[tid + 1024];
    hist[tid] = 0;
    if (tid == 0) { ctrL = 0; b1sh = 0; }
    __syncthreads();
    for (int s = 512; s > 0; s >>= 1) {
        if (tid < s) redA[tid] += redA[tid + s];
        __syncthreads();
    }
    if (tid == 0) zsh = redA[0];

    // (b) pass 1: histogram, burst-loaded (all 12 loads in flight per thread)
    {
        float4 r[BURST];
        #pragma unroll
        for (int j = 0; j < BURST; ++j) r[j] = s4[tid + j * 1024];
        float4 rt;
        if (tid < TAIL4) rt = s4[BURST * 1024 + tid];

        #pragma unroll
        for (int j = 0; j < BURST; ++j) {
            u32 b;
            b = __float_as_uint(r[j].x); if (b) atomicAdd(&hist[b >> BINSHIFT], 1u);
            b = __float_as_uint(r[j].y); if (b) atomicAdd(&hist[b >> BINSHIFT], 1u);
            b = __float_as_uint(r[j].z); if (b) atomicAdd(&hist[b >> BINSHIFT], 1u);
            b = __float_as_uint(r[j].w); if (b) atomicAdd(&hist[b >> BINSHIFT], 1u);
        }
        if (tid < TAIL4) {
            u32 b;
            b = __float_as_uint(rt.x); if (b) atomicAdd(&hist[b >> BINSHIFT], 1u);
            b = __float_as_uint(rt.y); if (b) atomicAdd(&hist[b >> BINSHIFT], 1u);
            b = __float_as_uint(rt.z); if (b) atomicAdd(&hist[b >> BINSHIFT], 1u);
            b = __float_as_uint(rt.w); if (b) atomicAdd(&hist[b >> BINSHIFT], 1u);
        }
    }
    __syncthreads();

    // (c) suffix scan (ping-pong, one barrier per step); result lands in hist
    {
        u32* src = hist;
        u32* dst = sufb;
        for (int s = 1; s < 1024; s <<= 1) {
            dst[tid] = src[tid] + ((tid + s < 1024) ? src[tid + s] : 0u);
            __syncthreads();
            u32* t_ = src; src = dst; dst = t_;
        }
        // 10 swaps (even) -> src == hist holds the suffix sums
        if (src[tid] >= (u32)TOPK && (tid == 1023 || src[tid + 1] < (u32)TOPK))
            b1sh = tid;                              // exactly one thread
    }
    __syncthreads();
    const int b1 = b1sh;

    // (d) pass 2: compact bin >= b1 (reads now cache-hot)
    {
        float4 r[BURST];
        #pragma unroll
        for (int j = 0; j < BURST; ++j) r[j] = s4[tid + j * 1024];
        float4 rt;
        if (tid < TAIL4) rt = s4[BURST * 1024 + tid];

        #pragma unroll
        for (int j = 0; j < BURST; ++j) {
            const int base = (tid + j * 1024) * 4;
            u32 b;
            b = __float_as_uint(r[j].x);
            if (b && (int)(b >> BINSHIFT) >= b1) { u32 p = atomicAdd(&ctrL, 1u); if (p < CAP) L[p] = ((u64)b << 32) | (u64)(0xFFFFFFFFu - (u32)(base + 0)); }
            b = __float_as_uint(r[j].y);
            if (b && (int)(b >> BINSHIFT) >= b1) { u32 p = atomicAdd(&ctrL, 1u); if (p < CAP) L[p] = ((u64)b << 32) | (u64)(0xFFFFFFFFu - (u32)(base + 1)); }
            b = __float_as_uint(r[j].z);
            if (b && (int)(b >> BINSHIFT) >= b1) { u32 p = atomicAdd(&ctrL, 1u); if (p < CAP) L[p] = ((u64)b << 32) | (u64)(0xFFFFFFFFu - (u32)(base + 2)); }
            b = __float_as_uint(r[j].w);
            if (b && (int)(b >> BINSHIFT) >= b1) { u32 p = atomicAdd(&ctrL, 1u); if (p < CAP) L[p] = ((u64)b << 32) | (u64)(0xFFFFFFFFu - (u32)(base + 3)); }
        }
        if (tid < TAIL4) {
            const int base = (BURST * 1024 + tid) * 4;
            u32 b;
            b = __float_as_uint(rt.x);
            if (b && (int)(b >> BINSHIFT) >= b1) { u32 p = atomicAdd(&ctrL, 1u); if (p < CAP) L[p] = ((u64)b << 32) | (u64)(0xFFFFFFFFu - (u32)(base + 0)); }
            b = __float_as_uint(rt.y);
            if (b && (int)(b >> BINSHIFT) >= b1) { u32 p = atomicAdd(&ctrL, 1u); if (p < CAP) L[p] = ((u64)b << 32) | (u64)(0xFFFFFFFFu - (u32)(base + 1)); }
            b = __float_as_uint(rt.z);
            if (b && (int)(b >> BINSHIFT) >= b1) { u32 p = atomicAdd(&ctrL, 1u); if (p < CAP) L[p] = ((u64)b << 32) | (u64)(0xFFFFFFFFu - (u32)(base + 2)); }
            b = __float_as_uint(rt.w);
            if (b && (int)(b >> BINSHIFT) >= b1) { u32 p = atomicAdd(&ctrL, 1u); if (p < CAP) L[p] = ((u64)b << 32) | (u64)(0xFFFFFFFFu - (u32)(base + 3)); }
        }
    }
    __syncthreads();

    // (e) rank-sort L (unique keys -> unique ranks); keep ranks < 25.
    // ctrL >= 25 by construction of b1 (suffix count at b1 >= TOPK).
    const int nL = (int)((ctrL < (u32)CAP) ? ctrL : (u32)CAP);
    for (int i = tid; i < nL; i += 1024) {
        const u64 ki = L[i];
        int rank = 0;
        for (int j = 0; j < nL; ++j) rank += (L[j] > ki);   // LDS broadcast reads
        if (rank < TOPK) Ls[rank] = ki;
    }
    __syncthreads();

    if (tid < TOPK) {
        const u64 kk = Ls[tid];
        topw[tid] = expf(__uint_as_float((u32)(kk >> 32)));
        topi[tid] = (int)(0xFFFFFFFFu - (u32)(kk & 0xFFFFFFFFu));
    }
    __syncthreads();

    // (f) oia gather + 3 dots.  attention_j = exp(s_j)/Z * 2*sigmoid(temp)
    const float gate  = 2.f / (1.f + expf(-temp_vid[0]));
    const float scale = gate / zsh;
    float oia_ = 0.f;
    if (tid < OD) {
        #pragma unroll
        for (int j = 0; j < TOPK; ++j)
            oia_ = fmaf(topw[j] * scale, n_answ[(size_t)topi[j] * OD + tid], oia_);
    }
    redA[tid] = (tid < OD) ? oia_ * o[0 * OD + tid] : 0.f;
    redB[tid] = (tid < OD) ? oia_ * o[1 * OD + tid] : 0.f;
    redC[tid] = (tid < OD) ? oia_ * o[2 * OD + tid] : 0.f;
    __syncthreads();
    for (int s = 512; s > 0; s >>= 1) {
        if (tid < s) {
            redA[tid] += redA[tid + s];
            redB[tid] += redB[tid + s];
            redC[tid] += redC[tid + s];
        }
        __syncthreads();
    }
    if (tid == 0) { out[0] = redA[0]; out[1] = redB[0]; out[2] = redC[0]; }
}

// ---------------------------------------------------------------------------
extern "C" void kernel_launch(void* const* d_in, const int* in_sizes, int n_in,
                              void* d_out, int out_size, void* d_ws, size_t ws_size,
                              hipStream_t stream)
{
    // setup_inputs order:
    // 0 v, 1 n_feats, 2 aud, 3 n_auds, 4 ocr, 5 n_ocrs, 6 o, 7 n_answ,
    // 8 temp_vid, 9 temp_aud, 10 temp_ocr
    const float* v        = (const float*)d_in[0];
    const float* n_feats  = (const float*)d_in[1];
    const float* o        = (const float*)d_in[6];
    const float* n_answ   = (const float*)d_in[7];
    const float* temp_vid = (const float*)d_in[8];
    // aud/ocr branches are multiplied by exactly 0.0 in the reference -> skipped.
    float* out = (float*)d_out;

    char* ws = (char*)d_ws;
    float* ws_s    = (float*)(ws);           // 50000 f32 = 200000 B (16B aligned)
    float* ws_part = (float*)(ws + 200704);  // 2048 f32  = 8192 B

    k_scores<<<K1_BLOCKS, K1_THREADS, 0, stream>>>(v, n_feats, ws_s, ws_part);
    k_finish<<<1, 1024, 0, stream>>>((const float4*)ws_s, ws_part, n_answ, o,
                                     temp_vid, out);
}